// Round 4
// baseline (236.302 us; speedup 1.0000x reference)
//
#include <hip/hip_runtime.h>

typedef unsigned int u32;
typedef unsigned short u16;
typedef float f4 __attribute__((ext_vector_type(4)));
typedef __bf16 b8 __attribute__((ext_vector_type(8)));
typedef unsigned short us8 __attribute__((ext_vector_type(8)));

#define DD 64
#define NE 16
#define OO 512
#define TR 64

struct __align__(16) Tile { u32 pid, slot, nr, pad; };

union U8 { us8 u; b8 b; };

__device__ __forceinline__ u16 f2bf(float f) {
  u32 u = __float_as_uint(f);
  u32 r = (u + 0x7fffu + ((u >> 16) & 1u)) >> 16;
  return (u16)r;
}

// ---------------- fused: blocks 0..127 transpose We; blocks 128..383 gate ----------------
__global__ void k_prep(const float* __restrict__ We, u16* __restrict__ WeT,
                       const float* __restrict__ x, const float* __restrict__ wg,
                       const float* __restrict__ bg, u32* __restrict__ hist,
                       u32* __restrict__ pid_arr, float* __restrict__ glo_arr,
                       float* __restrict__ ghi_arr) {
  __shared__ float tl[64][65];
  __shared__ u32 hcnt[256];
  int t = threadIdx.x;

  if (blockIdx.x < 128) {
    // ---- We [e][d][o] fp32 -> WeT [e][o][d] bf16 ----
    int b = blockIdx.x;
    int e = b >> 3;
    int oc = (b & 7) * 64;
    int d = t >> 2, seg = (t & 3) * 16;
    const f4* src = (const f4*)(We + ((size_t)(e * DD + d)) * OO + oc + seg);
    f4 v0 = src[0], v1 = src[1], v2 = src[2], v3 = src[3];
#pragma unroll
    for (int j = 0; j < 4; j++) {
      tl[d][seg + j]      = v0[j];
      tl[d][seg + 4 + j]  = v1[j];
      tl[d][seg + 8 + j]  = v2[j];
      tl[d][seg + 12 + j] = v3[j];
    }
    __syncthreads();
    int o = t >> 2, ds = (t & 3) * 16;
    us8 o0, o1;
#pragma unroll
    for (int j = 0; j < 8; j++) {
      o0[j] = f2bf(tl[ds + j][o]);
      o1[j] = f2bf(tl[ds + 8 + j][o]);
    }
    u16* dst = WeT + ((size_t)(e * OO + oc + o)) * DD + ds;
    *(us8*)dst = o0;
    *(us8*)(dst + 8) = o1;
    return;
  }

  // ---- gating: softmax -> top2 -> (pid, g_lo, g_hi); per-block hist, LDS atomics ----
  int gb = blockIdx.x - 128;
  hcnt[t] = 0;
  __syncthreads();
  int row = gb * 256 + t;

  float l[NE];
#pragma unroll
  for (int e = 0; e < NE; e++) l[e] = bg[e];

  const f4* xp = (const f4*)(x + (size_t)row * DD);
  for (int d4 = 0; d4 < 16; d4++) {
    f4 xv = xp[d4];
#pragma unroll
    for (int qq = 0; qq < 4; qq++) {
      float xs = xv[qq];
      const float* wrow = wg + (d4 * 4 + qq) * NE;
#pragma unroll
      for (int e = 0; e < NE; e++) l[e] = fmaf(xs, wrow[e], l[e]);
    }
  }
  float mx = l[0];
#pragma unroll
  for (int e = 1; e < NE; e++) mx = fmaxf(mx, l[e]);
  float Z = 0.f;
#pragma unroll
  for (int e = 0; e < NE; e++) Z += __expf(l[e] - mx);
  int i1 = 0; float b1 = l[0];
#pragma unroll
  for (int e = 1; e < NE; e++) { if (l[e] > b1) { b1 = l[e]; i1 = e; } }
  int i2 = -1; float b2 = -1e30f;
#pragma unroll
  for (int e = 0; e < NE; e++) { if (e != i1 && l[e] > b2) { b2 = l[e]; i2 = e; } }
  float p1 = __expf(b1 - mx) / Z;
  float p2 = __expf(b2 - mx) / Z;
  float den = p1 + p2 + 1e-6f;   // reference: top_vals / (sum(top_vals) + 1e-6)
  float g1 = p1 / den, g2 = p2 / den;
  int elo, ehi; float glo, ghi;
  if (i1 < i2) { elo = i1; ehi = i2; glo = g1; ghi = g2; }
  else         { elo = i2; ehi = i1; glo = g2; ghi = g1; }
  u32 pid = (u32)(elo * NE + ehi);
  pid_arr[row] = pid;
  glo_arr[row] = glo;
  ghi_arr[row] = ghi;
  atomicAdd(&hcnt[pid], 1u);
  __syncthreads();
  hist[gb * 256 + t] = hcnt[t];
}

// ---------------- per-pid scan over gate-blocks: hist[b][p] -> local exclusive, tot[p] ----------------
__global__ void k_colscan(u32* __restrict__ hist, u32* __restrict__ tot) {
  __shared__ u32 s[256];
  int b = threadIdx.x, p = blockIdx.x;
  u32 v = hist[b * 256 + p];
  s[b] = v;
  __syncthreads();
  for (int d = 1; d < 256; d <<= 1) {
    u32 a = 0;
    if (b >= d) a = s[b - d];
    __syncthreads();
    s[b] += a;
    __syncthreads();
  }
  hist[b * 256 + p] = s[b] - v;
  if (b == 255) tot[p] = s[255];
}

// ---------------- scan totals -> per-pid base + tile descriptors ----------------
__global__ void k_base(const u32* __restrict__ tot, u32* __restrict__ base,
                       u32* __restrict__ ntp, Tile* __restrict__ tiles) {
  __shared__ u32 s[256], s2[256];
  int t = threadIdx.x;
  u32 v = tot[t];
  u32 nt = (v + (TR - 1)) >> 6;
  s[t] = v; s2[t] = nt;
  __syncthreads();
  for (int d = 1; d < 256; d <<= 1) {
    u32 a = 0, c = 0;
    if (t >= d) { a = s[t - d]; c = s2[t - d]; }
    __syncthreads();
    s[t] += a; s2[t] += c;
    __syncthreads();
  }
  u32 rb = s[t] - v;
  u32 tb = s2[t] - nt;
  base[t] = rb;
  for (u32 k = 0; k < nt; k++) {
    Tile td;
    td.pid = (u32)t;
    td.slot = rb + k * (u32)TR;
    u32 rem = v - k * (u32)TR;
    td.nr = rem < (u32)TR ? rem : (u32)TR;
    td.pad = 0;
    tiles[tb + k] = td;
  }
  if (t == 255) *ntp = s2[255];
}

// ---------------- scatter rows into pair buckets (LDS atomics only) ----------------
__global__ void k_scatter(const u32* __restrict__ pid_arr, const u32* __restrict__ hist,
                          const u32* __restrict__ base, u32* __restrict__ sorted) {
  __shared__ u32 lcnt[256], lbase[256];
  int t = threadIdx.x;
  lcnt[t] = 0;
  lbase[t] = base[t];
  __syncthreads();
  int row = blockIdx.x * 256 + t;
  u32 pid = pid_arr[row];
  u32 rank = atomicAdd(&lcnt[pid], 1u);
  u32 off = lbase[pid] + hist[blockIdx.x * 256 + pid];
  sorted[off + rank] = (u32)row;
}

// ---------------- main: barrier-free, LDS-free pair-tile GEMM ----------------
// Operand swap: A = WeT slice (m = output col), B = x rows (n = batch row).
// D[m][n]: lane(q,ln) holds o = otile+q*4+rr (4 consecutive cols), row = ln.
// -> direct float4 stores, 64B/row/instr, paired ot covers full 128B lines.
__global__ void k_moe(const float* __restrict__ x, const u16* __restrict__ WeT,
                      const float* __restrict__ be, const u32* __restrict__ sorted,
                      const u32* __restrict__ ntp, const Tile* __restrict__ tiles,
                      const float* __restrict__ glo_arr, const float* __restrict__ ghi_arr,
                      float* __restrict__ y) {
  u32 bid = blockIdx.x;
  if (bid >= *ntp) return;
  Tile td = tiles[bid];
  u32 e_lo = td.pid >> 4, e_hi = td.pid & 15u;
  u32 slot0 = td.slot, nr = td.nr;

  int t = threadIdx.x;
  int w = t >> 6;
  int lane = t & 63;
  int q = lane >> 4;
  int ln = lane & 15;

  int i = w * 16 + ln;                 // row index within tile, 0..63
  bool valid = (u32)i < nr;
  u32 slot = slot0 + (valid ? (u32)i : 0u);
  u32 rid = sorted[slot];
  float gl = valid ? glo_arr[rid] : 0.f;
  float gh = valid ? ghi_arr[rid] : 0.f;

  // B-fragments: B[k=q*8+j+32*kc][n=ln] = x[rid][d] as bf16
  const float* xr = x + (size_t)rid * DD;
  f4 xa = *(const f4*)(xr + q * 8);
  f4 xb = *(const f4*)(xr + q * 8 + 4);
  f4 xc = *(const f4*)(xr + 32 + q * 8);
  f4 xd = *(const f4*)(xr + 32 + q * 8 + 4);
  U8 bu0, bu1;
#pragma unroll
  for (int j = 0; j < 4; j++) {
    bu0.u[j] = f2bf(xa[j]); bu0.u[4 + j] = f2bf(xb[j]);
    bu1.u[j] = f2bf(xc[j]); bu1.u[4 + j] = f2bf(xd[j]);
  }
  b8 bf0 = bu0.b, bf1 = bu1.b;

  const u16* wlo = WeT + (size_t)e_lo * OO * DD;
  const u16* whi = WeT + (size_t)e_hi * OO * DD;
  const float* bel = be + (size_t)e_lo * OO;
  const float* beh = be + (size_t)e_hi * OO;
  float* yrow = y + (size_t)rid * OO;
  const f4 zero = {0.f, 0.f, 0.f, 0.f};

#pragma unroll
  for (int oo = 0; oo < 4; oo++) {
#pragma unroll
    for (int otp = 0; otp < 4; otp++) {
      f4 vout[2];
#pragma unroll
      for (int h = 0; h < 2; h++) {
        int ot = otp * 2 + h;
        int col = oo * 128 + ot * 16 + ln;         // A m-index = ln
        const us8* pl = (const us8*)(wlo + (size_t)col * DD + q * 8);
        const us8* ph = (const us8*)(whi + (size_t)col * DD + q * 8);
        U8 a0, a1, a2, a3;
        a0.u = pl[0]; a1.u = pl[4];                // k-chunks 0 / 1
        a2.u = ph[0]; a3.u = ph[4];
        f4 aL = zero, aH = zero;
        aL = __builtin_amdgcn_mfma_f32_16x16x32_bf16(a0.b, bf0, aL, 0, 0, 0);
        aL = __builtin_amdgcn_mfma_f32_16x16x32_bf16(a1.b, bf1, aL, 0, 0, 0);
        aH = __builtin_amdgcn_mfma_f32_16x16x32_bf16(a2.b, bf0, aH, 0, 0, 0);
        aH = __builtin_amdgcn_mfma_f32_16x16x32_bf16(a3.b, bf1, aH, 0, 0, 0);
        int c0 = oo * 128 + ot * 16 + q * 4;       // this lane's 4 cols
        f4 bL = *(const f4*)(bel + c0);
        f4 bH = *(const f4*)(beh + c0);
        f4 v;
#pragma unroll
        for (int rr = 0; rr < 4; rr++)
          v[rr] = gl * (aL[rr] + bL[rr]) + gh * (aH[rr] + bH[rr]);
        vout[h] = v;
      }
      if (valid) {
        int c0 = oo * 128 + otp * 32 + q * 4;
        *(f4*)(yrow + c0)      = vout[0];          // back-to-back: full 128B line
        *(f4*)(yrow + c0 + 16) = vout[1];
      }
    }
  }
}

extern "C" void kernel_launch(void* const* d_in, const int* in_sizes, int n_in,
                              void* d_out, int out_size, void* d_ws, size_t ws_size,
                              hipStream_t stream) {
  const float* x  = (const float*)d_in[0];
  const float* wg = (const float*)d_in[1];
  const float* bg = (const float*)d_in[2];
  const float* We = (const float*)d_in[3];
  const float* be = (const float*)d_in[4];
  float* y = (float*)d_out;

  char* ws = (char*)d_ws;
  u32* ntp     = (u32*)(ws + 0);                       // 1 u32
  Tile* tiles  = (Tile*)(ws + 4096);                   // <= 1344 * 16B
  u32* pid_arr = (u32*)(ws + 32768);                   // 65536 u32
  float* glo_a = (float*)(ws + 32768 + 262144);        // 65536 f32
  float* ghi_a = (float*)(ws + 32768 + 2 * 262144);    // 65536 f32
  u32* sorted  = (u32*)(ws + 32768 + 3 * 262144);      // 65536 u32
  u16* WeT     = (u16*)(ws + 32768 + 4 * 262144);      // 524288 bf16 (1MB)
  u32* hist    = (u32*)(ws + 32768 + 4 * 262144 + 1048576);            // 256*256 u32
  u32* tot     = (u32*)(ws + 32768 + 4 * 262144 + 1048576 + 262144);   // 256 u32
  u32* base    = (u32*)(ws + 32768 + 4 * 262144 + 1048576 + 262144 + 1024); // 256 u32

  k_prep<<<384, 256, 0, stream>>>(We, WeT, x, wg, bg, hist, pid_arr, glo_a, ghi_a);
  k_colscan<<<256, 256, 0, stream>>>(hist, tot);
  k_base<<<1, 256, 0, stream>>>(tot, base, ntp, tiles);
  k_scatter<<<256, 256, 0, stream>>>(pid_arr, hist, base, sorted);
  k_moe<<<1144, 256, 0, stream>>>(x, WeT, be, sorted, ntp, tiles, glo_a, ghi_a, y);
}